// Round 12
// baseline (205.076 us; speedup 1.0000x reference)
//
#include <hip/hip_runtime.h>
#include <hip/hip_bf16.h>
#include <cstdint>
#include <cstddef>

using u16 = unsigned short;
using u32 = uint32_t;
using f32x4  = __attribute__((ext_vector_type(4))) float;
using bf16x8 = __attribute__((ext_vector_type(8))) __bf16;
using s16x4  = __attribute__((ext_vector_type(4))) short;   // 4 bf16 raw bits

#define D_MODEL 1024
#define N_HEADS 16
#define HD      64
#define SEQ     2048
#define QKV_LD  3072   // 3*D_MODEL, row stride of qkv
#define K2SCALE 0.18033688011112042f   // 0.125 * log2(e), folded into Q

// ---------- helpers ----------
__device__ __forceinline__ u16 f2b(float f) {           // fp32 -> bf16 RNE
  union { float f; u32 u; } v; v.f = f;
  u32 r = 0x7FFFu + ((v.u >> 16) & 1u);
  return (u16)((v.u + r) >> 16);
}

// packed pair via v_cvt_pk_bf16_f32 (gfx950); a->lo16, b->hi16
__device__ __forceinline__ u32 pkbf16(float a, float b) {
  union { __hip_bfloat162 h; u32 u; } c;
  c.h = __float22bfloat162_rn(float2{a, b});
  return c.u;
}

// NOTE: do NOT gate amdgcn builtins on __has_builtin (false on host pass).
#define MFMA16(A, B, C) __builtin_amdgcn_mfma_f32_16x16x16bf16_1k(A, B, C, 0, 0, 0)

__device__ __forceinline__ void gld16(const u16* g, u16* l) {
  // async global->LDS, 16B per lane; LDS dest = wave-uniform base + lane*16
  __builtin_amdgcn_global_load_lds(
      (const __attribute__((address_space(1))) void*)g,
      (__attribute__((address_space(3))) void*)l, 16, 0, 0);
}

// ---------- fused fp32 -> bf16 cast of x, w_qkv, w_proj (dst contiguous) ----
__global__ void cast3_bf16(const float* __restrict__ x, const float* __restrict__ wq,
                           const float* __restrict__ wp, u16* __restrict__ dst) {
  int i = blockIdx.x * blockDim.x + threadIdx.x;        // float4 index
  const float* src;
  int off;
  if (blockIdx.x < 4096)      { src = x;  off = 0; }
  else if (blockIdx.x < 7168) { src = wq; off = 4096 * 256; }
  else                        { src = wp; off = 7168 * 256; }
  float4 f = ((const float4*)src)[i - off];
  u32 lo = pkbf16(f.x, f.y), hi = pkbf16(f.z, f.w);
  uint2 o = {lo, hi};
  ((uint2*)dst)[i] = o;
}

// ---------- NT GEMM: C[M,N] = A[M,K] * B[N,K]^T  (bf16 in, fp32 acc) ----------
// KC/NC compile-time: staging addresses strength-reduce to base + kk*64B.
// Single-barrier pipelined K-loop, unroll-2 (cur becomes a literal).
// OUTMODE 0: bf16 out, cols < D_MODEL pre-scaled by K2SCALE.  1: fp32 + bias.
template<int OUTMODE, int MT, int KC, int NC>
__launch_bounds__(256, 3)
__global__ void gemm_nt(const u16* __restrict__ A, const u16* __restrict__ B,
                        u16* __restrict__ Ob, float* __restrict__ Of,
                        const float* __restrict__ bias) {
  __shared__ __attribute__((aligned(16))) u16 sA[2][MT * 32];
  __shared__ __attribute__((aligned(16))) u16 sB[2][128 * 32];

  const int tid  = threadIdx.x;
  const int lane = tid & 63;
  const int w    = tid >> 6;
  const int qd   = lane >> 4;      // quad 0..3
  const int ln   = lane & 15;
  constexpr int MI = MT / 32;      // m-subtiles per wave (4 or 2)
  constexpr int AC = MT / 64;      // A staging calls per wave
  const int wm   = (w >> 1) * (MT / 2);
  const int wn   = (w & 1) * 64;
  const int m0   = blockIdx.y * MT;
  const int n0   = blockIdx.x * 128;

  // hoisted per-lane staging pointers (K-loop adds kk*32 elements only)
  const u16* aP[AC]; u16* aL[2][AC];
  #pragma unroll
  for (int c = 0; c < AC; ++c) {
    int s = w * MT + c * 64 + lane;
    aP[c] = A + (size_t)(m0 + (s >> 2)) * KC + (s & 3) * 8;
    aL[0][c] = &sA[0][(w * MT + c * 64) * 8];
    aL[1][c] = &sA[1][(w * MT + c * 64) * 8];
  }
  const u16* bP[2]; u16* bL[2][2];
  #pragma unroll
  for (int c = 0; c < 2; ++c) {
    int s = w * 128 + c * 64 + lane;
    bP[c] = B + (size_t)(n0 + (s >> 2)) * KC + (s & 3) * 8;
    bL[0][c] = &sB[0][(w * 128 + c * 64) * 8];
    bL[1][c] = &sB[1][(w * 128 + c * 64) * 8];
  }

  auto stage = [&](int kk, int buf) {
    int k0 = kk * 32;
    #pragma unroll
    for (int c = 0; c < AC; ++c) gld16(aP[c] + k0, aL[buf][c]);
    #pragma unroll
    for (int c = 0; c < 2; ++c)  gld16(bP[c] + k0, bL[buf][c]);
  };

  f32x4 acc[MI][4] = {};
  constexpr int NK = KC / 32;
  stage(0, 0);

  #pragma unroll 2
  for (int kk = 0; kk < NK; ++kk) {
    const int cur = kk & 1;
    __syncthreads();
    if (kk + 1 < NK) stage(kk + 1, cur ^ 1);

    bf16x8 af[MI], bfm[4];
    #pragma unroll
    for (int i = 0; i < MI; ++i)
      af[i] = *(const bf16x8*)&sA[cur][(wm + i * 16 + ln) * 32 + qd * 8];
    #pragma unroll
    for (int j = 0; j < 4; ++j)
      bfm[j] = *(const bf16x8*)&sB[cur][(wn + j * 16 + ln) * 32 + qd * 8];
    #pragma unroll
    for (int i = 0; i < MI; ++i)
      #pragma unroll
      for (int j = 0; j < 4; ++j)
        acc[i][j] = __builtin_amdgcn_mfma_f32_16x16x32_bf16(af[i], bfm[j], acc[i][j], 0, 0, 0);
  }

  // epilogue: C/D layout col=lane&15, row=quad*4+reg (R9 scalar form)
  #pragma unroll
  for (int i = 0; i < MI; ++i) {
    #pragma unroll
    for (int j = 0; j < 4; ++j) {
      #pragma unroll
      for (int r = 0; r < 4; ++r) {
        int row = m0 + wm + i * 16 + qd * 4 + r;
        int col = n0 + wn + j * 16 + ln;
        float v = acc[i][j][r];
        if (OUTMODE == 0) {
          if (col < D_MODEL) v *= K2SCALE;   // uniform per block (n0 mult of 128)
          Ob[(size_t)row * NC + col] = f2b(v);
        } else {
          Of[(size_t)row * NC + col] = v + bias[col];
        }
      }
    }
  }
}

// ---------- flash attention: R9 structure + MFMA-computed softmax sums ----------
// S^T = K Q^T (C-layout lane: col=qrow=ln, rows=keys qd*4+r) feeds 16x16x16 PV
// as B-operand directly. Row sums via MFMA16(ones, P^T): hardware cross-lane
// key-sum -> no per-lane adds, no final shuffles.
__launch_bounds__(256, 2)
__global__ void attn_kernel(const u16* __restrict__ qkv, u16* __restrict__ outb) {
  __shared__ __attribute__((aligned(16))) u16 sK[2][2][128 * 32]; // [buf][hf] 32 KB
  __shared__ __attribute__((aligned(16))) u32 sVT[2][64 * 64];    // [buf] 32 KB

  const int tid  = threadIdx.x;
  const int lane = tid & 63;
  const int w    = tid >> 6;
  const int qd   = lane >> 4;
  const int ln   = lane & 15;
  const int qp   = blockIdx.x;            // 0..15, 128-row Q pair-tile
  const int h    = blockIdx.y & 15;
  const int b    = blockIdx.y >> 4;
  const size_t tokbase = (size_t)b * SEQ;
  const int q0   = qp * 128;
  const int qoff = h * HD;
  const int koff = D_MODEL + h * HD;
  const int voff = 2 * D_MODEL + h * HD;

  // Q fragments: 2 chains (q-rows q0+c2*64+w*16+ln), B-operand layout
  bf16x8 aq[2][2];
  #pragma unroll
  for (int c2 = 0; c2 < 2; ++c2)
    #pragma unroll
    for (int hf = 0; hf < 2; ++hf)
      aq[c2][hf] = *(const bf16x8*)(qkv + (tokbase + q0 + c2 * 64 + w * 16 + ln) * QKV_LD
                                    + qoff + hf * 32 + qd * 8);

  auto stageK = [&](int kt, int buf) {
    #pragma unroll
    for (int hf = 0; hf < 2; ++hf)
      #pragma unroll
      for (int c = 0; c < 2; ++c) {
        int sbase = w * 128 + c * 64;
        int s = sbase + lane;
        int row = s >> 2, col = (s & 3) * 8;
        gld16(qkv + (tokbase + kt * 128 + row) * QKV_LD + koff + hf * 32 + col,
              &sK[buf][hf][sbase * 8]);
      }
  };
  auto loadV = [&](int kt, uint4* va, uint4* vb) {
    #pragma unroll
    for (int it = 0; it < 2; ++it) {
      int j = it * 256 + tid;
      int tp = j & 63, d0 = (j >> 6) * 8;
      const u16* g0 = qkv + (tokbase + kt * 128 + tp * 2) * QKV_LD + voff + d0;
      va[it] = *(const uint4*)g0;
      vb[it] = *(const uint4*)(g0 + QKV_LD);
    }
  };
  auto writeV = [&](int buf, const uint4* va, const uint4* vb) {
    #pragma unroll
    for (int it = 0; it < 2; ++it) {
      int j = it * 256 + tid;
      int tp = j & 63, d0 = (j >> 6) * 8;   // d0 multiple of 8
      const u32* a  = (const u32*)&va[it];
      const u32* bb = (const u32*)&vb[it];
      #pragma unroll
      for (int e = 0; e < 4; ++e) {
        sVT[buf][(d0 + 2 * e    ) * 64 + (tp ^ (e << 4)    )] =
            __builtin_amdgcn_perm(bb[e], a[e], 0x05040100u);
        sVT[buf][(d0 + 2 * e + 1) * 64 + (tp ^ (e << 4) ^ 8)] =
            __builtin_amdgcn_perm(bb[e], a[e], 0x07060302u);
      }
    }
  };

  // prologue: K(0) async -> sK[0]; V(0) -> sVT[0]; V(1) -> regs
  stageK(0, 0);
  uint4 va[2], vb[2];
  loadV(0, va, vb);
  writeV(0, va, vb);
  loadV(1, va, vb);

  f32x4 accOT[2][4] = {};          // O^T per chain: row d=ob*16+qd*4+r, col=ln
  f32x4 accPS[2] = {};             // softmax denominators via MFMA (all regs equal)
  const s16x4 vf1 = {0x3F80, 0x3F80, 0x3F80, 0x3F80};   // bf16 1.0 x4
  const int tsw = (ln & 7) << 3;   // sVT read-side XOR swizzle

  for (int kt = 0; kt < 16; ++kt) {
    const int cur = kt & 1, nxt = cur ^ 1;
    __syncthreads();
    if (kt < 15) { stageK(kt + 1, nxt); writeV(nxt, va, vb); }
    if (kt < 14) { loadV(kt + 2, va, vb); }

    #pragma unroll
    for (int cb = 0; cb < 8; ++cb) {
      bf16x8 ak0 = *(const bf16x8*)&sK[cur][0][(cb * 16 + ln) * 32 + qd * 8];
      bf16x8 ak1 = *(const bf16x8*)&sK[cur][1][(cb * 16 + ln) * 32 + qd * 8];
      f32x4 st[2];
      #pragma unroll
      for (int c2 = 0; c2 < 2; ++c2) {
        f32x4 z = {0.f, 0.f, 0.f, 0.f};
        f32x4 t = __builtin_amdgcn_mfma_f32_16x16x32_bf16(ak0, aq[c2][0], z, 0, 0, 0);
        st[c2]  = __builtin_amdgcn_mfma_f32_16x16x32_bf16(ak1, aq[c2][1], t, 0, 0, 0);
      }
      s16x4 pf[2];
      #pragma unroll
      for (int c2 = 0; c2 < 2; ++c2) {
        float p0 = __builtin_amdgcn_exp2f(st[c2][0]);
        float p1 = __builtin_amdgcn_exp2f(st[c2][1]);
        float p2 = __builtin_amdgcn_exp2f(st[c2][2]);
        float p3 = __builtin_amdgcn_exp2f(st[c2][3]);
        union { u32 d[2]; s16x4 v; } pk;
        pk.d[0] = pkbf16(p0, p1);        // v_cvt_pk_bf16_f32
        pk.d[1] = pkbf16(p2, p3);
        pf[c2] = pk.v;
        accPS[c2] = MFMA16(vf1, pf[c2], accPS[c2]);   // denominator via matrix pipe
      }
      #pragma unroll
      for (int ob = 0; ob < 4; ++ob) {
        s16x4 vf = *(const s16x4*)&sVT[cur][(ob * 16 + ln) * 64
                                           + ((cb * 8 + qd * 2) ^ tsw)];
        accOT[0][ob] = MFMA16(vf, pf[0], accOT[0][ob]);
        accOT[1][ob] = MFMA16(vf, pf[1], accOT[1][ob]);
      }
    }
  }

  // denominators: accPS rows are identical; qrow=ln sum is in any reg
  float rinv[2];
  rinv[0] = 1.0f / accPS[0][0];
  rinv[1] = 1.0f / accPS[1][0];

  // transpose O^T -> O through LDS (reuse sK), coalesced bf16 stores
  u16* sOut = (u16*)&sK[0][0][0];        // [128 tokens][72] u16 = 18 KB
  __syncthreads();
  #pragma unroll
  for (int c2 = 0; c2 < 2; ++c2)
    #pragma unroll
    for (int ob = 0; ob < 4; ++ob) {
      u32 lo = pkbf16(accOT[c2][ob][0] * rinv[c2], accOT[c2][ob][1] * rinv[c2]);
      u32 hi = pkbf16(accOT[c2][ob][2] * rinv[c2], accOT[c2][ob][3] * rinv[c2]);
      ((u32*)sOut)[(c2 * 64 + w * 16 + ln) * 36 + ob * 8 + qd * 2    ] = lo;
      ((u32*)sOut)[(c2 * 64 + w * 16 + ln) * 36 + ob * 8 + qd * 2 + 1] = hi;
    }
  __syncthreads();
  #pragma unroll
  for (int it = 0; it < 4; ++it) {
    int idx = it * 256 + tid;            // 0..1023
    int token = idx >> 3, chunk = idx & 7;
    uint4 v = *(const uint4*)&sOut[token * 72 + chunk * 8];
    *(uint4*)&outb[(tokbase + q0 + token) * D_MODEL + h * HD + chunk * 8] = v;
  }
}

// ---------- launch ----------
extern "C" void kernel_launch(void* const* d_in, const int* in_sizes, int n_in,
                              void* d_out, int out_size, void* d_ws, size_t ws_size,
                              hipStream_t stream) {
  const float* x      = (const float*)d_in[0];   // [4096,1024]
  const float* w_qkv  = (const float*)d_in[1];   // [3072,1024]
  const float* w_proj = (const float*)d_in[2];   // [1024,1024]
  const float* b_proj = (const float*)d_in[3];   // [1024]
  float* out = (float*)d_out;                    // [4096,1024]

  u16* ws     = (u16*)d_ws;
  u16* xb     = ws;                                   // 4096*1024
  u16* wqkvb  = xb    + (size_t)4096 * 1024;          // 3072*1024
  u16* wprojb = wqkvb + (size_t)3072 * 1024;          // 1024*1024
  u16* qkvb   = wprojb + (size_t)1024 * 1024;         // 4096*3072
  u16* attnb  = qkvb  + (size_t)4096 * 3072;          // 4096*1024

  // one fused cast: dst regions xb|wqkvb|wprojb are contiguous
  cast3_bf16<<<8192, 256, 0, stream>>>(x, w_qkv, w_proj, xb);

  // qkv = x @ w_qkv^T -> [4096,3072] bf16 (Q pre-scaled); 768 blocks = 3/CU
  gemm_nt<0, 128, 1024, 3072><<<dim3(24, 32), 256, 0, stream>>>(
      xb, wqkvb, qkvb, nullptr, nullptr);

  // attention -> [4096,1024] bf16; 512 blocks x 256 threads, 2/CU
  attn_kernel<<<dim3(16, 32), 256, 0, stream>>>(qkvb, attnb);

  // out = attn @ w_proj^T + b_proj -> fp32; 64x128 tiles, 512 blocks
  gemm_nt<1, 64, 1024, 1024><<<dim3(8, 64), 256, 0, stream>>>(
      attnb, wprojb, nullptr, out, b_proj);
}

// Round 13
// 186.063 us; speedup vs baseline: 1.1022x; 1.1022x over previous
//
#include <hip/hip_runtime.h>
#include <hip/hip_bf16.h>
#include <cstdint>
#include <cstddef>

using u16 = unsigned short;
using u32 = uint32_t;
using f32x4  = __attribute__((ext_vector_type(4))) float;
using bf16x8 = __attribute__((ext_vector_type(8))) __bf16;
using s16x4  = __attribute__((ext_vector_type(4))) short;   // 4 bf16 raw bits

#define D_MODEL 1024
#define N_HEADS 16
#define HD      64
#define SEQ     2048
#define QKV_LD  3072   // 3*D_MODEL, row stride of qkv
#define K2SCALE 0.18033688011112042f   // 0.125 * log2(e), folded into Q

// ---------- helpers ----------
__device__ __forceinline__ u16 f2b(float f) {           // fp32 -> bf16 RNE
  union { float f; u32 u; } v; v.f = f;
  u32 r = 0x7FFFu + ((v.u >> 16) & 1u);
  return (u16)((v.u + r) >> 16);
}

// packed pair via v_cvt_pk_bf16_f32 (gfx950); a->lo16, b->hi16
__device__ __forceinline__ u32 pkbf16(float a, float b) {
  union { __hip_bfloat162 h; u32 u; } c;
  c.h = __float22bfloat162_rn(float2{a, b});
  return c.u;
}

// NOTE: do NOT gate amdgcn builtins on __has_builtin (false on host pass).
#define MFMA16(A, B, C) __builtin_amdgcn_mfma_f32_16x16x16bf16_1k(A, B, C, 0, 0, 0)

__device__ __forceinline__ void gld16(const u16* g, u16* l) {
  // async global->LDS, 16B per lane; LDS dest = wave-uniform base + lane*16
  __builtin_amdgcn_global_load_lds(
      (const __attribute__((address_space(1))) void*)g,
      (__attribute__((address_space(3))) void*)l, 16, 0, 0);
}

// ---------- fused fp32 -> bf16 cast of x, w_qkv, w_proj (dst contiguous) ----
__global__ void cast3_bf16(const float* __restrict__ x, const float* __restrict__ wq,
                           const float* __restrict__ wp, u16* __restrict__ dst) {
  int i = blockIdx.x * blockDim.x + threadIdx.x;        // float4 index
  const float* src;
  int off;
  if (blockIdx.x < 4096)      { src = x;  off = 0; }
  else if (blockIdx.x < 7168) { src = wq; off = 4096 * 256; }
  else                        { src = wp; off = 7168 * 256; }
  float4 f = ((const float4*)src)[i - off];
  u32 lo = pkbf16(f.x, f.y), hi = pkbf16(f.z, f.w);
  uint2 o = {lo, hi};
  ((uint2*)dst)[i] = o;
}

// ---------- NT GEMM (R9 form): C[M,N] = A[M,K] * B[N,K]^T  (bf16, fp32 acc) ----
// Single-barrier pipelined K-loop. MT = M-tile (128 or 64); N-tile fixed 128.
// OUTMODE 0: bf16 out, cols < D_MODEL pre-scaled by K2SCALE.  1: fp32 + bias.
template<int OUTMODE, int MT>
__launch_bounds__(256, 3)
__global__ void gemm_nt(const u16* __restrict__ A, const u16* __restrict__ B,
                        u16* __restrict__ Ob, float* __restrict__ Of,
                        const float* __restrict__ bias, int N, int K) {
  __shared__ __attribute__((aligned(16))) u16 sA[2][MT * 32];
  __shared__ __attribute__((aligned(16))) u16 sB[2][128 * 32];

  const int tid  = threadIdx.x;
  const int lane = tid & 63;
  const int w    = tid >> 6;
  const int qd   = lane >> 4;      // quad 0..3
  const int ln   = lane & 15;
  constexpr int MI = MT / 32;      // m-subtiles per wave (4 or 2)
  const int wm   = (w >> 1) * (MT / 2);
  const int wn   = (w & 1) * 64;
  const int m0   = blockIdx.y * MT;
  const int n0   = blockIdx.x * 128;

  auto stage = [&](int kk, int buf) {
    int k0 = kk * 32;
    #pragma unroll
    for (int c = 0; c < MT / 64; ++c) {      // A, 16B/lane
      int sbase = w * MT + c * 64;
      int s = sbase + lane;
      int row = s >> 2, col = (s & 3) * 8;
      gld16(A + (size_t)(m0 + row) * K + k0 + col, &sA[buf][sbase * 8]);
    }
    #pragma unroll
    for (int c = 0; c < 2; ++c) {            // B
      int sbase = w * 128 + c * 64;
      int s = sbase + lane;
      int row = s >> 2, col = (s & 3) * 8;
      gld16(B + (size_t)(n0 + row) * K + k0 + col, &sB[buf][sbase * 8]);
    }
  };

  f32x4 acc[MI][4] = {};
  const int NK = K >> 5;
  stage(0, 0);

  for (int kk = 0; kk < NK; ++kk) {
    const int cur = kk & 1;
    __syncthreads();
    if (kk + 1 < NK) stage(kk + 1, cur ^ 1);

    bf16x8 af[MI], bfm[4];
    #pragma unroll
    for (int i = 0; i < MI; ++i)
      af[i] = *(const bf16x8*)&sA[cur][(wm + i * 16 + ln) * 32 + qd * 8];
    #pragma unroll
    for (int j = 0; j < 4; ++j)
      bfm[j] = *(const bf16x8*)&sB[cur][(wn + j * 16 + ln) * 32 + qd * 8];
    #pragma unroll
    for (int i = 0; i < MI; ++i)
      #pragma unroll
      for (int j = 0; j < 4; ++j)
        acc[i][j] = __builtin_amdgcn_mfma_f32_16x16x32_bf16(af[i], bfm[j], acc[i][j], 0, 0, 0);
  }

  // epilogue: C/D layout col=lane&15, row=quad*4+reg
  #pragma unroll
  for (int i = 0; i < MI; ++i) {
    #pragma unroll
    for (int j = 0; j < 4; ++j) {
      #pragma unroll
      for (int r = 0; r < 4; ++r) {
        int row = m0 + wm + i * 16 + qd * 4 + r;
        int col = n0 + wn + j * 16 + ln;
        float v = acc[i][j][r];
        if (OUTMODE == 0) {
          if (col < D_MODEL) v *= K2SCALE;   // uniform per block (n0 mult of 128)
          Ob[(size_t)row * N + col] = f2b(v);
        } else {
          Of[(size_t)row * N + col] = v + bias[col];
        }
      }
    }
  }
}

// ---------- flash attention: KT=64 key tiles, 32 KB LDS -> 3 blocks/CU ----------
// R9 wave structure (4 waves x 2 chains, 128-row Q tile) with half-size K/V
// tiles: same per-key staging & LDS-read amortization, +50% TLP to cover the
// latency stalls. sVT swizzle rescaled to 32 cols: f(d)=(d&7)*4, tsw=(ln&7)<<2.
__launch_bounds__(256, 3)
__global__ void attn_kernel(const u16* __restrict__ qkv, u16* __restrict__ outb) {
  // carved pool: sK 16 KB + sVT 16 KB = 32 KB; epilogue reuses it (needs 18.4 KB)
  __shared__ __attribute__((aligned(16))) u16 smem[16384];
  u16 (*sK)[2][64 * 32] = (u16(*)[2][64 * 32])smem;       // [buf][hf]
  u32 (*sVT)[64 * 32]   = (u32(*)[64 * 32])(smem + 8192); // [buf]

  const int tid  = threadIdx.x;
  const int lane = tid & 63;
  const int w    = tid >> 6;
  const int qd   = lane >> 4;
  const int ln   = lane & 15;
  const int qp   = blockIdx.x;            // 0..15, 128-row Q pair-tile
  const int h    = blockIdx.y & 15;
  const int b    = blockIdx.y >> 4;
  const size_t tokbase = (size_t)b * SEQ;
  const int q0   = qp * 128;
  const int qoff = h * HD;
  const int koff = D_MODEL + h * HD;
  const int voff = 2 * D_MODEL + h * HD;

  // Q fragments: 2 chains (q-rows q0+c2*64+w*16+ln), B-operand layout
  bf16x8 aq[2][2];
  #pragma unroll
  for (int c2 = 0; c2 < 2; ++c2)
    #pragma unroll
    for (int hf = 0; hf < 2; ++hf)
      aq[c2][hf] = *(const bf16x8*)(qkv + (tokbase + q0 + c2 * 64 + w * 16 + ln) * QKV_LD
                                    + qoff + hf * 32 + qd * 8);

  auto stageK = [&](int kt, int buf) {
    // 64 rows x 32 cols per hf = 4 KB = 256 lanes x 16B: one gld16/wave/hf
    #pragma unroll
    for (int hf = 0; hf < 2; ++hf) {
      int s = w * 64 + lane;               // 0..255
      int row = s >> 2, col = (s & 3) * 8;
      gld16(qkv + (tokbase + kt * 64 + row) * QKV_LD + koff + hf * 32 + col,
            &sK[buf][hf][w * 512]);
    }
  };
  auto loadV = [&](int kt, uint4& va, uint4& vb) {
    int tp = tid & 31, d0 = (tid >> 5) * 8;
    const u16* g0 = qkv + (tokbase + kt * 64 + tp * 2) * QKV_LD + voff + d0;
    va = *(const uint4*)g0;
    vb = *(const uint4*)(g0 + QKV_LD);
  };
  auto writeV = [&](int buf, const uint4& va, const uint4& vb) {
    int tp = tid & 31, d0 = (tid >> 5) * 8;  // d0 multiple of 8
    const u32* a  = (const u32*)&va;
    const u32* bb = (const u32*)&vb;
    #pragma unroll
    for (int e = 0; e < 4; ++e) {
      sVT[buf][(d0 + 2 * e    ) * 32 + (tp ^ (e << 3)    )] =
          __builtin_amdgcn_perm(bb[e], a[e], 0x05040100u);
      sVT[buf][(d0 + 2 * e + 1) * 32 + (tp ^ (e << 3) ^ 4)] =
          __builtin_amdgcn_perm(bb[e], a[e], 0x07060302u);
    }
  };

  // prologue: K(0) async -> sK[0]; V(0) -> sVT[0]; V(1) -> regs
  stageK(0, 0);
  uint4 va, vb;
  loadV(0, va, vb);
  writeV(0, va, vb);
  loadV(1, va, vb);

  f32x4 accOT[2][4] = {};          // O^T per chain: row d=ob*16+qd*4+r, col=ln
  float psum[2] = {0.f, 0.f};
  const int tsw = (ln & 7) << 2;   // sVT read-side XOR swizzle (32-col variant)

  for (int kt = 0; kt < 32; ++kt) {
    const int cur = kt & 1, nxt = cur ^ 1;
    __syncthreads();
    if (kt < 31) { stageK(kt + 1, nxt); writeV(nxt, va, vb); }
    if (kt < 30) { loadV(kt + 2, va, vb); }

    #pragma unroll
    for (int cb = 0; cb < 4; ++cb) {
      bf16x8 ak0 = *(const bf16x8*)&sK[cur][0][(cb * 16 + ln) * 32 + qd * 8];
      bf16x8 ak1 = *(const bf16x8*)&sK[cur][1][(cb * 16 + ln) * 32 + qd * 8];
      f32x4 st[2];
      #pragma unroll
      for (int c2 = 0; c2 < 2; ++c2) {
        f32x4 z = {0.f, 0.f, 0.f, 0.f};
        f32x4 t = __builtin_amdgcn_mfma_f32_16x16x32_bf16(ak0, aq[c2][0], z, 0, 0, 0);
        st[c2]  = __builtin_amdgcn_mfma_f32_16x16x32_bf16(ak1, aq[c2][1], t, 0, 0, 0);
      }
      s16x4 pf[2];
      #pragma unroll
      for (int c2 = 0; c2 < 2; ++c2) {
        float p0 = __builtin_amdgcn_exp2f(st[c2][0]);
        float p1 = __builtin_amdgcn_exp2f(st[c2][1]);
        float p2 = __builtin_amdgcn_exp2f(st[c2][2]);
        float p3 = __builtin_amdgcn_exp2f(st[c2][3]);
        psum[c2] += (p0 + p1) + (p2 + p3);
        union { u32 d[2]; s16x4 v; } pk;
        pk.d[0] = pkbf16(p0, p1);        // v_cvt_pk_bf16_f32
        pk.d[1] = pkbf16(p2, p3);
        pf[c2] = pk.v;
      }
      #pragma unroll
      for (int ob = 0; ob < 4; ++ob) {
        s16x4 vf = *(const s16x4*)&sVT[cur][(ob * 16 + ln) * 32
                                           + ((cb * 8 + qd * 2) ^ tsw)];
        accOT[0][ob] = MFMA16(vf, pf[0], accOT[0][ob]);
        accOT[1][ob] = MFMA16(vf, pf[1], accOT[1][ob]);
      }
    }
  }

  // row-sum completion: reduce across the 4 quads (lanes ln, +16, +32, +48)
  #pragma unroll
  for (int c2 = 0; c2 < 2; ++c2) {
    float s = psum[c2];
    s += __shfl_xor(s, 16, 64);
    s += __shfl_xor(s, 32, 64);
    psum[c2] = 1.0f / s;
  }

  // transpose O^T -> O through LDS (reuse smem), coalesced bf16 stores
  u16* sOut = smem;                      // [128 tokens][72] u16 = 18 KB
  __syncthreads();
  #pragma unroll
  for (int c2 = 0; c2 < 2; ++c2)
    #pragma unroll
    for (int ob = 0; ob < 4; ++ob) {
      u32 lo = pkbf16(accOT[c2][ob][0] * psum[c2], accOT[c2][ob][1] * psum[c2]);
      u32 hi = pkbf16(accOT[c2][ob][2] * psum[c2], accOT[c2][ob][3] * psum[c2]);
      ((u32*)sOut)[(c2 * 64 + w * 16 + ln) * 36 + ob * 8 + qd * 2    ] = lo;
      ((u32*)sOut)[(c2 * 64 + w * 16 + ln) * 36 + ob * 8 + qd * 2 + 1] = hi;
    }
  __syncthreads();
  #pragma unroll
  for (int it = 0; it < 4; ++it) {
    int idx = it * 256 + tid;            // 0..1023
    int token = idx >> 3, chunk = idx & 7;
    uint4 v = *(const uint4*)&sOut[token * 72 + chunk * 8];
    *(uint4*)&outb[(tokbase + q0 + token) * D_MODEL + h * HD + chunk * 8] = v;
  }
}

// ---------- launch ----------
extern "C" void kernel_launch(void* const* d_in, const int* in_sizes, int n_in,
                              void* d_out, int out_size, void* d_ws, size_t ws_size,
                              hipStream_t stream) {
  const float* x      = (const float*)d_in[0];   // [4096,1024]
  const float* w_qkv  = (const float*)d_in[1];   // [3072,1024]
  const float* w_proj = (const float*)d_in[2];   // [1024,1024]
  const float* b_proj = (const float*)d_in[3];   // [1024]
  float* out = (float*)d_out;                    // [4096,1024]

  u16* ws     = (u16*)d_ws;
  u16* xb     = ws;                                   // 4096*1024
  u16* wqkvb  = xb    + (size_t)4096 * 1024;          // 3072*1024
  u16* wprojb = wqkvb + (size_t)3072 * 1024;          // 1024*1024
  u16* qkvb   = wprojb + (size_t)1024 * 1024;         // 4096*3072
  u16* attnb  = qkvb  + (size_t)4096 * 3072;          // 4096*1024

  // one fused cast: dst regions xb|wqkvb|wprojb are contiguous
  cast3_bf16<<<8192, 256, 0, stream>>>(x, w_qkv, w_proj, xb);

  // qkv = x @ w_qkv^T -> [4096,3072] bf16 (Q pre-scaled); 768 blocks = 3/CU
  gemm_nt<0, 128><<<dim3(24, 32), 256, 0, stream>>>(xb, wqkvb, qkvb, nullptr, nullptr, 3072, 1024);

  // attention -> [4096,1024] bf16; 512 blocks x 256 threads, 3/CU
  attn_kernel<<<dim3(16, 32), 256, 0, stream>>>(qkvb, attnb);

  // out = attn @ w_proj^T + b_proj -> fp32; 64x128 tiles, 512 blocks
  gemm_nt<1, 64><<<dim3(8, 64), 256, 0, stream>>>(attnb, wprojb, nullptr, out, b_proj, 1024, 1024);
}